// Round 1
// baseline (254.692 us; speedup 1.0000x reference)
//
#include <hip/hip_runtime.h>
#include <math.h>

#define Bn 8
#define Cc 512
#define Nn 4096   // 64*64
#define Mm 1024   // 32*32 pooled
#define C8 64
#define C2 256

// ---------------- always-on path ----------------

// xm[b,c] = mean_n x[b,c,n]
__global__ void mean_kernel(const float* __restrict__ x, float* __restrict__ xm) {
    int bc = blockIdx.x;                       // 0..B*C-1
    int t = threadIdx.x;                       // 256
    const float4* r4 = (const float4*)(x + (size_t)bc * Nn);
    float s = 0.f;
    for (int i = t; i < Nn / 4; i += 256) {
        float4 v = r4[i];
        s += v.x + v.y + v.z + v.w;
    }
    __shared__ float red[4];
    for (int off = 32; off; off >>= 1) s += __shfl_down(s, off);
    if ((t & 63) == 0) red[t >> 6] = s;
    __syncthreads();
    if (t == 0) xm[bc] = (red[0] + red[1] + red[2] + red[3]) * (1.f / Nn);
}

// y[b,o] = sigmoid( relu(xm @ fc1^T) @ fc2^T )
__global__ void se_kernel(const float* __restrict__ xm, const float* __restrict__ fc1,
                          const float* __restrict__ fc2, float* __restrict__ yv) {
    int b = blockIdx.x, t = threadIdx.x;
    int wv = t >> 6, ln = t & 63;
    __shared__ float sx[Cc];
    __shared__ float sh[C2];
    for (int i = t; i < Cc; i += 256) sx[i] = xm[b * Cc + i];
    __syncthreads();
    for (int j = wv; j < C2; j += 4) {
        float a = 0.f;
        const float* w1 = fc1 + (size_t)j * Cc;
        for (int c = ln; c < Cc; c += 64) a += sx[c] * w1[c];
        for (int off = 32; off; off >>= 1) a += __shfl_down(a, off);
        if (ln == 0) sh[j] = fmaxf(a, 0.f);
    }
    __syncthreads();
    for (int o = wv; o < Cc; o += 4) {
        float a = 0.f;
        const float* w2 = fc2 + (size_t)o * C2;
        for (int j = ln; j < C2; j += 64) a += sh[j] * w2[j];
        for (int off = 32; off; off >>= 1) a += __shfl_down(a, off);
        if (ln == 0) yv[b * Cc + o] = 1.f / (1.f + expf(-a));
    }
}

// out = gamma*(wo @ ao + bo) + x*y   (attention term skipped entirely when gamma==0)
__global__ void final_kernel(const float* __restrict__ x, const float* __restrict__ ao,
                             const float* __restrict__ wo, const float* __restrict__ bo,
                             const float* __restrict__ yv, const float* __restrict__ gamma,
                             float* __restrict__ out) {
    int t = threadIdx.x;
    int n4 = blockIdx.x * 256 + t;             // float4 index, grid.x = N/1024
    int o = blockIdx.y, b = blockIdx.z;
    float g = gamma[0];
    float yb = yv[b * Cc + o];
    size_t base = ((size_t)(b * Cc + o)) * Nn;
    float4 xv = ((const float4*)(x + base))[n4];
    float4 r;
    r.x = xv.x * yb; r.y = xv.y * yb; r.z = xv.z * yb; r.w = xv.w * yb;
    if (g != 0.f) {
        int n = n4 * 4;
        const float* wrow = wo + (size_t)o * C2;
        float a0 = 0, a1 = 0, a2 = 0, a3 = 0;
        for (int c2 = 0; c2 < C2; c2++) {
            const float* arow = ao + ((size_t)(b * C2 + c2)) * Nn + n;
            float wv_ = wrow[c2];
            a0 += wv_ * arow[0]; a1 += wv_ * arow[1];
            a2 += wv_ * arow[2]; a3 += wv_ * arow[3];
        }
        float bb = bo[o];
        r.x += g * (a0 + bb); r.y += g * (a1 + bb);
        r.z += g * (a2 + bb); r.w += g * (a3 + bb);
    }
    ((float4*)(out + base))[n4] = r;
}

// ---------------- gamma-guarded attention path (general-case correctness) ----------------

// q[b,o,n] = wq[o,:] . x[b,:,n] + bq[o]
__global__ void convq_kernel(const float* __restrict__ x, const float* __restrict__ wq,
                             const float* __restrict__ bq, float* __restrict__ q,
                             const float* __restrict__ gamma) {
    if (gamma[0] == 0.f) return;
    int n = blockIdx.x * 256 + threadIdx.x;
    int o = blockIdx.y, b = blockIdx.z;
    const float* xb = x + (size_t)b * Cc * Nn + n;
    const float* w = wq + (size_t)o * Cc;
    float acc = 0.f;
    for (int c = 0; c < Cc; c++) acc += w[c] * xb[(size_t)c * Nn];
    q[((size_t)(b * C8 + o)) * Nn + n] = acc + bq[o];
}

// out[b,o,m] = maxpool2( w[o,:] . x[b,:,.] + bias[o] )
template <int O>
__global__ void convpool_kernel(const float* __restrict__ x, const float* __restrict__ w,
                                const float* __restrict__ bias, float* __restrict__ out,
                                const float* __restrict__ gamma) {
    if (gamma[0] == 0.f) return;
    int m = blockIdx.x * 256 + threadIdx.x;    // 0..1023
    int o = blockIdx.y, b = blockIdx.z;
    int wm = m >> 5, hm = m & 31;
    int n0 = wm * 128 + hm * 2;                // (2wm)*64 + 2hm
    const float* xb = x + (size_t)b * Cc * Nn;
    const float* wr = w + (size_t)o * Cc;
    float a0 = 0, a1 = 0, a2 = 0, a3 = 0;
    for (int c = 0; c < Cc; c++) {
        const float* xc = xb + (size_t)c * Nn + n0;
        float wv_ = wr[c];
        a0 += wv_ * xc[0]; a1 += wv_ * xc[1];
        a2 += wv_ * xc[64]; a3 += wv_ * xc[65];
    }
    out[((size_t)(b * O + o)) * Mm + m] = fmaxf(fmaxf(a0, a1), fmaxf(a2, a3)) + bias[o];
}

// per (b,n): energy row -> softmax -> ao[b,:,n] = v @ attn_row
__global__ void attn_kernel(const float* __restrict__ q, const float* __restrict__ kp,
                            const float* __restrict__ vp, float* __restrict__ ao,
                            const float* __restrict__ gamma) {
    if (gamma[0] == 0.f) return;
    int n = blockIdx.x, b = blockIdx.y, t = threadIdx.x;
    __shared__ float qs[C8];
    __shared__ float ps[Mm];
    __shared__ float red[4];
    if (t < C8) qs[t] = q[((size_t)(b * C8 + t)) * Nn + n];
    __syncthreads();
    float e[4];
    for (int j = 0; j < 4; j++) {
        int m = t + j * 256;
        float a = 0.f;
        for (int c = 0; c < C8; c++) a += qs[c] * kp[((size_t)(b * C8 + c)) * Mm + m];
        e[j] = a;
    }
    float mx = fmaxf(fmaxf(e[0], e[1]), fmaxf(e[2], e[3]));
    for (int off = 32; off; off >>= 1) mx = fmaxf(mx, __shfl_down(mx, off));
    if ((t & 63) == 0) red[t >> 6] = mx;
    __syncthreads();
    mx = fmaxf(fmaxf(red[0], red[1]), fmaxf(red[2], red[3]));
    float s = 0.f;
    for (int j = 0; j < 4; j++) {
        float p = expf(e[j] - mx);
        ps[t + j * 256] = p;
        s += p;
    }
    for (int off = 32; off; off >>= 1) s += __shfl_down(s, off);
    __syncthreads();
    if ((t & 63) == 0) red[t >> 6] = s;
    __syncthreads();
    float inv = 1.f / (red[0] + red[1] + red[2] + red[3]);
    // c2 == t (C2 == blockDim)
    float a = 0.f;
    const float* vrow = vp + ((size_t)(b * C2 + t)) * Mm;
    for (int mm = 0; mm < Mm; mm++) a += vrow[mm] * ps[mm];
    ao[((size_t)(b * C2 + t)) * Nn + n] = a * inv;
}

// ---------------- launch ----------------

extern "C" void kernel_launch(void* const* d_in, const int* in_sizes, int n_in,
                              void* d_out, int out_size, void* d_ws, size_t ws_size,
                              hipStream_t stream) {
    const float* x   = (const float*)d_in[0];
    const float* wq  = (const float*)d_in[1];
    const float* bq  = (const float*)d_in[2];
    const float* wk  = (const float*)d_in[3];
    const float* bk  = (const float*)d_in[4];
    const float* wv  = (const float*)d_in[5];
    const float* bv  = (const float*)d_in[6];
    const float* wo  = (const float*)d_in[7];
    const float* bo  = (const float*)d_in[8];
    const float* fc1 = (const float*)d_in[9];
    const float* fc2 = (const float*)d_in[10];
    const float* gm  = (const float*)d_in[11];
    float* out = (float*)d_out;
    float* ws  = (float*)d_ws;

    // small always-used buffers first (32 KB); big guarded scratch after
    float* xm = ws;                       // B*C
    float* yv = xm + Bn * Cc;             // B*C
    float* q  = yv + Bn * Cc;             // B*C8*N
    float* kp = q  + (size_t)Bn * C8 * Nn; // B*C8*M
    float* vp = kp + (size_t)Bn * C8 * Mm; // B*C2*M
    float* ao = vp + (size_t)Bn * C2 * Mm; // B*C2*N

    mean_kernel<<<dim3(Bn * Cc), dim3(256), 0, stream>>>(x, xm);
    se_kernel<<<dim3(Bn), dim3(256), 0, stream>>>(xm, fc1, fc2, yv);

    convq_kernel<<<dim3(Nn / 256, C8, Bn), dim3(256), 0, stream>>>(x, wq, bq, q, gm);
    convpool_kernel<C8><<<dim3(Mm / 256, C8, Bn), dim3(256), 0, stream>>>(x, wk, bk, kp, gm);
    convpool_kernel<C2><<<dim3(Mm / 256, C2, Bn), dim3(256), 0, stream>>>(x, wv, bv, vp, gm);
    attn_kernel<<<dim3(Nn, Bn), dim3(256), 0, stream>>>(q, kp, vp, ao, gm);

    final_kernel<<<dim3(Nn / 1024, Cc, Bn), dim3(256), 0, stream>>>(x, ao, wo, bo, yv, gm, out);
}

// Round 2
// 57.862 us; speedup vs baseline: 4.4017x; 4.4017x over previous
//
#include <hip/hip_runtime.h>
#include <math.h>

#define Bn 8
#define Cc 512
#define Nn 4096   // 64*64
#define Mm 1024   // 32*32 pooled
#define C8 64
#define C2 256

// ---------------- always-on path ----------------

// xm[b,c] = mean_n x[b,c,n]
__global__ void mean_kernel(const float* __restrict__ x, float* __restrict__ xm) {
    int bc = blockIdx.x;                       // 0..B*C-1
    int t = threadIdx.x;                       // 256
    const float4* r4 = (const float4*)(x + (size_t)bc * Nn);
    float s = 0.f;
    for (int i = t; i < Nn / 4; i += 256) {
        float4 v = r4[i];
        s += v.x + v.y + v.z + v.w;
    }
    __shared__ float red[4];
    for (int off = 32; off; off >>= 1) s += __shfl_down(s, off);
    if ((t & 63) == 0) red[t >> 6] = s;
    __syncthreads();
    if (t == 0) xm[bc] = (red[0] + red[1] + red[2] + red[3]) * (1.f / Nn);
}

// h[b,j] = relu(xm[b,:] . fc1[j,:])   — one wave per (j,b)
__global__ void se1_kernel(const float* __restrict__ xm, const float* __restrict__ fc1,
                           float* __restrict__ hbuf) {
    int j = blockIdx.x, b = blockIdx.y, ln = threadIdx.x;   // 64 threads
    const float* w1 = fc1 + (size_t)j * Cc;
    const float* xb = xm + b * Cc;
    float a = 0.f;
    #pragma unroll
    for (int k = 0; k < Cc / 64; k++) a += xb[ln + k * 64] * w1[ln + k * 64];
    for (int off = 32; off; off >>= 1) a += __shfl_down(a, off);
    if (ln == 0) hbuf[b * C2 + j] = fmaxf(a, 0.f);
}

// y[b,o] = sigmoid(h[b,:] . fc2[o,:]) — one wave per (o,b)
__global__ void se2_kernel(const float* __restrict__ hbuf, const float* __restrict__ fc2,
                           float* __restrict__ yv) {
    int o = blockIdx.x, b = blockIdx.y, ln = threadIdx.x;   // 64 threads
    const float* w2 = fc2 + (size_t)o * C2;
    const float* hb = hbuf + b * C2;
    float a = 0.f;
    #pragma unroll
    for (int k = 0; k < C2 / 64; k++) a += hb[ln + k * 64] * w2[ln + k * 64];
    for (int off = 32; off; off >>= 1) a += __shfl_down(a, off);
    if (ln == 0) yv[b * Cc + o] = 1.f / (1.f + expf(-a));
}

// out = gamma*(wo @ ao + bo) + x*y   (attention term skipped entirely when gamma==0)
__global__ void final_kernel(const float* __restrict__ x, const float* __restrict__ ao,
                             const float* __restrict__ wo, const float* __restrict__ bo,
                             const float* __restrict__ yv, const float* __restrict__ gamma,
                             float* __restrict__ out) {
    int t = threadIdx.x;
    int n4 = blockIdx.x * 256 + t;             // float4 index, grid.x = N/1024
    int o = blockIdx.y, b = blockIdx.z;
    float g = gamma[0];
    float yb = yv[b * Cc + o];
    size_t base = ((size_t)(b * Cc + o)) * Nn;
    float4 xv = ((const float4*)(x + base))[n4];
    float4 r;
    r.x = xv.x * yb; r.y = xv.y * yb; r.z = xv.z * yb; r.w = xv.w * yb;
    if (g != 0.f) {
        int n = n4 * 4;
        const float* wrow = wo + (size_t)o * C2;
        float a0 = 0, a1 = 0, a2 = 0, a3 = 0;
        for (int c2 = 0; c2 < C2; c2++) {
            const float* arow = ao + ((size_t)(b * C2 + c2)) * Nn + n;
            float wv_ = wrow[c2];
            a0 += wv_ * arow[0]; a1 += wv_ * arow[1];
            a2 += wv_ * arow[2]; a3 += wv_ * arow[3];
        }
        float bb = bo[o];
        r.x += g * (a0 + bb); r.y += g * (a1 + bb);
        r.z += g * (a2 + bb); r.w += g * (a3 + bb);
    }
    ((float4*)(out + base))[n4] = r;
}

// ---------------- gamma-guarded attention path (general-case correctness) ----------------

// q[b,o,n] = wq[o,:] . x[b,:,n] + bq[o]
__global__ void convq_kernel(const float* __restrict__ x, const float* __restrict__ wq,
                             const float* __restrict__ bq, float* __restrict__ q,
                             const float* __restrict__ gamma) {
    if (gamma[0] == 0.f) return;
    int n = blockIdx.x * 256 + threadIdx.x;
    int o = blockIdx.y, b = blockIdx.z;
    const float* xb = x + (size_t)b * Cc * Nn + n;
    const float* w = wq + (size_t)o * Cc;
    float acc = 0.f;
    for (int c = 0; c < Cc; c++) acc += w[c] * xb[(size_t)c * Nn];
    q[((size_t)(b * C8 + o)) * Nn + n] = acc + bq[o];
}

// out[b,o,m] = maxpool2( w[o,:] . x[b,:,.] + bias[o] )
template <int O>
__global__ void convpool_kernel(const float* __restrict__ x, const float* __restrict__ w,
                                const float* __restrict__ bias, float* __restrict__ out,
                                const float* __restrict__ gamma) {
    if (gamma[0] == 0.f) return;
    int m = blockIdx.x * 256 + threadIdx.x;    // 0..1023
    int o = blockIdx.y, b = blockIdx.z;
    int wm = m >> 5, hm = m & 31;
    int n0 = wm * 128 + hm * 2;                // (2wm)*64 + 2hm
    const float* xb = x + (size_t)b * Cc * Nn;
    const float* wr = w + (size_t)o * Cc;
    float a0 = 0, a1 = 0, a2 = 0, a3 = 0;
    for (int c = 0; c < Cc; c++) {
        const float* xc = xb + (size_t)c * Nn + n0;
        float wv_ = wr[c];
        a0 += wv_ * xc[0]; a1 += wv_ * xc[1];
        a2 += wv_ * xc[64]; a3 += wv_ * xc[65];
    }
    out[((size_t)(b * O + o)) * Mm + m] = fmaxf(fmaxf(a0, a1), fmaxf(a2, a3)) + bias[o];
}

// per (b,n): energy row -> softmax -> ao[b,:,n] = v @ attn_row
__global__ void attn_kernel(const float* __restrict__ q, const float* __restrict__ kp,
                            const float* __restrict__ vp, float* __restrict__ ao,
                            const float* __restrict__ gamma) {
    if (gamma[0] == 0.f) return;
    int n = blockIdx.x, b = blockIdx.y, t = threadIdx.x;
    __shared__ float qs[C8];
    __shared__ float ps[Mm];
    __shared__ float red[4];
    if (t < C8) qs[t] = q[((size_t)(b * C8 + t)) * Nn + n];
    __syncthreads();
    float e[4];
    for (int j = 0; j < 4; j++) {
        int m = t + j * 256;
        float a = 0.f;
        for (int c = 0; c < C8; c++) a += qs[c] * kp[((size_t)(b * C8 + c)) * Mm + m];
        e[j] = a;
    }
    float mx = fmaxf(fmaxf(e[0], e[1]), fmaxf(e[2], e[3]));
    for (int off = 32; off; off >>= 1) mx = fmaxf(mx, __shfl_down(mx, off));
    if ((t & 63) == 0) red[t >> 6] = mx;
    __syncthreads();
    mx = fmaxf(fmaxf(red[0], red[1]), fmaxf(red[2], red[3]));
    float s = 0.f;
    for (int j = 0; j < 4; j++) {
        float p = expf(e[j] - mx);
        ps[t + j * 256] = p;
        s += p;
    }
    for (int off = 32; off; off >>= 1) s += __shfl_down(s, off);
    __syncthreads();
    if ((t & 63) == 0) red[t >> 6] = s;
    __syncthreads();
    float inv = 1.f / (red[0] + red[1] + red[2] + red[3]);
    // c2 == t (C2 == blockDim)
    float a = 0.f;
    const float* vrow = vp + ((size_t)(b * C2 + t)) * Mm;
    for (int mm = 0; mm < Mm; mm++) a += vrow[mm] * ps[mm];
    ao[((size_t)(b * C2 + t)) * Nn + n] = a * inv;
}

// ---------------- launch ----------------

extern "C" void kernel_launch(void* const* d_in, const int* in_sizes, int n_in,
                              void* d_out, int out_size, void* d_ws, size_t ws_size,
                              hipStream_t stream) {
    const float* x   = (const float*)d_in[0];
    const float* wq  = (const float*)d_in[1];
    const float* bq  = (const float*)d_in[2];
    const float* wk  = (const float*)d_in[3];
    const float* bk  = (const float*)d_in[4];
    const float* wv  = (const float*)d_in[5];
    const float* bv  = (const float*)d_in[6];
    const float* wo  = (const float*)d_in[7];
    const float* bo  = (const float*)d_in[8];
    const float* fc1 = (const float*)d_in[9];
    const float* fc2 = (const float*)d_in[10];
    const float* gm  = (const float*)d_in[11];
    float* out = (float*)d_out;
    float* ws  = (float*)d_ws;

    // small always-used buffers first (40 KB); big guarded scratch after
    float* xm = ws;                        // B*C
    float* yv = xm + Bn * Cc;              // B*C
    float* hb = yv + Bn * Cc;              // B*C2
    float* q  = hb + Bn * C2;              // B*C8*N
    float* kp = q  + (size_t)Bn * C8 * Nn; // B*C8*M
    float* vp = kp + (size_t)Bn * C8 * Mm; // B*C2*M
    float* ao = vp + (size_t)Bn * C2 * Mm; // B*C2*N

    mean_kernel<<<dim3(Bn * Cc), dim3(256), 0, stream>>>(x, xm);
    se1_kernel<<<dim3(C2, Bn), dim3(64), 0, stream>>>(xm, fc1, hb);
    se2_kernel<<<dim3(Cc, Bn), dim3(64), 0, stream>>>(hb, fc2, yv);

    convq_kernel<<<dim3(Nn / 256, C8, Bn), dim3(256), 0, stream>>>(x, wq, bq, q, gm);
    convpool_kernel<C8><<<dim3(Mm / 256, C8, Bn), dim3(256), 0, stream>>>(x, wk, bk, kp, gm);
    convpool_kernel<C2><<<dim3(Mm / 256, C2, Bn), dim3(256), 0, stream>>>(x, wv, bv, vp, gm);
    attn_kernel<<<dim3(Nn, Bn), dim3(256), 0, stream>>>(q, kp, vp, ao, gm);

    final_kernel<<<dim3(Nn / 1024, Cc, Bn), dim3(256), 0, stream>>>(x, ao, wo, bo, yv, gm, out);
}